// Round 3
// baseline (305.062 us; speedup 1.0000x reference)
//
#include <hip/hip_runtime.h>
#include <float.h>

typedef __bf16 bf16x8 __attribute__((ext_vector_type(8)));
typedef __bf16 bf16x4 __attribute__((ext_vector_type(4)));
typedef float  f32x4  __attribute__((ext_vector_type(4)));

#define G      256
#define NPT    16      // points per wave-tile (MFMA N)
#define NW     8       // waves per block
#define H1DIM  64
#define H2DIM  128
#define LAT    256
#define A2PAD  136     // 272 B rows: 16B-aligned, 68 dw == 4 mod 32 -> 2-way (free) b128

// order-preserving float->uint map: max on uints == max on floats
__device__ __forceinline__ unsigned mapf(float f) {
  unsigned u = __float_as_uint(f);
  return (u & 0x80000000u) ? ~u : (u | 0x80000000u);
}
__device__ __forceinline__ float unmapf(unsigned u) {
  return (u & 0x80000000u) ? __uint_as_float(u & 0x7fffffffu) : __uint_as_float(~u);
}

// flush one 16-feature m-tile: add bias, reduce over the 16 point lanes, atomicMax.
// f32x4 passed BY VALUE (no address-taken on run[]).
__device__ __forceinline__ void flush_mt(f32x4 v4, int mt, int s, int q, int nn,
                                         const float* __restrict__ b3,
                                         unsigned* __restrict__ pooled) {
  #pragma unroll
  for (int r = 0; r < 4; ++r) {
    int feat = mt * 16 + q * 4 + r;
    float v = v4[r] + b3[feat];
    v = fmaxf(v, __shfl_xor(v, 1));
    v = fmaxf(v, __shfl_xor(v, 2));
    v = fmaxf(v, __shfl_xor(v, 4));
    v = fmaxf(v, __shfl_xor(v, 8));
    if (nn == 0) atomicMax(&pooled[s * LAT + feat], mapf(v));
  }
}

// ---------------- barrier-free fused centroid + MLP + segment max ----------------
// Round-1 lesson: 4 barrier-separated phases/tile with 2 chains/CU = 6100 cyc/tile
// for ~1000 cyc of work; adding waves to the lockstep chain was neutral.
// New structure: weights live in LDS (W2 16K + W3 64K, preloaded once, one barrier);
// each wave processes its OWN 16-point tile with wave-private LDS activation scratch
// (same-wave RAW needs only lgkmcnt, no barrier). Zero __syncthreads in main loop ->
// 8 independent wave-chains per CU. L1 weights + b1 folded into regs (bias in K-pad:
// B[k=4]=1.0, A[m][4]=b1[m]). LDS total 114.5 KB -> 1 block/CU.
__global__ __launch_bounds__(512, 2) void mlp_kernel(
    const float* __restrict__ pc,
    const float* __restrict__ W1, const float* __restrict__ b1,
    const float* __restrict__ W2, const float* __restrict__ b2,
    const float* __restrict__ W3, const float* __restrict__ b3,
    const int* __restrict__ sid,
    unsigned* __restrict__ pooled,
    float* __restrict__ sums,
    int n, int tiles_per_wave) {
  __shared__ bf16x8 w2lds[H2DIM / 16 * 2 * 64];            // [mt][ks][lane] 16 KB
  __shared__ bf16x8 w3lds[LAT / 16 * 4 * 64];              // [mt][ks][lane] 64 KB
  __shared__ __align__(16) float b2lds[H2DIM];             // 0.5 KB
  __shared__ __align__(16) __bf16 act[NW][NPT][A2PAD];     // 34 KB; act1 reuses act2 rows

  const int t    = threadIdx.x;
  const int w    = t >> 6;       // wave 0..7
  const int lane = t & 63;
  const int q    = lane >> 4;
  const int nn   = lane & 15;

  // ---- one-time cooperative weight preload into frag-layout LDS ----
  for (int idx = t; idx < LAT / 16 * 4 * 64; idx += 512) {   // 4096 entries
    int mt = idx >> 8, ks = (idx >> 6) & 3, l = idx & 63;
    int lq = l >> 4, lm = (mt << 4) + (l & 15);
    bf16x8 v;
    #pragma unroll
    for (int j = 0; j < 8; ++j)
      v[j] = (__bf16)W3[(ks * 32 + lq * 8 + j) * LAT + lm];
    w3lds[idx] = v;
  }
  for (int idx = t; idx < H2DIM / 16 * 2 * 64; idx += 512) { // 1024 entries
    int mt = idx >> 7, ks = (idx >> 6) & 1, l = idx & 63;
    int lq = l >> 4, lm = (mt << 4) + (l & 15);
    bf16x8 v;
    #pragma unroll
    for (int j = 0; j < 8; ++j)
      v[j] = (__bf16)W2[(ks * 32 + lq * 8 + j) * H2DIM + lm];
    w2lds[idx] = v;
  }
  if (t < H2DIM) b2lds[t] = b2[t];

  // per-wave L1 A-frags in regs, b1 folded into K-pad column k=4
  bf16x8 w1r[4];
  #pragma unroll
  for (int mt = 0; mt < 4; ++mt)
    #pragma unroll
    for (int j = 0; j < 8; ++j) {
      int k = q * 8 + j;
      float v = 0.f;
      if (k < 4)       v = W1[k * H1DIM + mt * 16 + nn];
      else if (k == 4) v = b1[mt * 16 + nn];
      w1r[mt][j] = (__bf16)v;
    }

  __syncthreads();   // the ONLY block-wide barrier

  const int gw = blockIdx.x * NW + w;                 // global wave id
  const int chunk_base = gw * tiles_per_wave * NPT;
  if (chunk_base >= n) return;

  const f32x4  zero4 = {0.f, 0.f, 0.f, 0.f};
  const bf16x8 zero8 = {};

  f32x4 run[16];                                      // running segment max (no bias)
  #pragma unroll
  for (int mt = 0; mt < 16; ++mt)
    run[mt] = (f32x4){-FLT_MAX, -FLT_MAX, -FLT_MAX, -FLT_MAX};

  // centroid state (q==0 lanes; each lane owns a sorted point stream)
  float cx = 0.f, cy = 0.f, cz = 0.f, cc = 0.f;
  int   cseg = -1;

  int s_cur = sid[chunk_base];

  // prefetch tile 0 (q==0 lanes)
  float pf1 = 0.f, pf2 = 0.f, pf3 = 0.f, pfx = 0.f;
  int pfs = 0; bool pfv = false;
  if (q == 0) {
    int p = chunk_base + nn;
    pfv = p < n;
    int pcl = pfv ? p : (n - 1);
    const float* pp = pc + (size_t)pcl * 5;
    pf1 = pp[1]; pf2 = pp[2]; pf3 = pp[3]; pfx = pp[4];
    pfs = sid[pcl];
  }

  for (int ti = 0; ti < tiles_per_wave; ++ti) {
    const int base = chunk_base + ti * NPT;
    if (base >= n) break;

    // consume prefetch; issue next-tile loads (in flight across whole tile)
    float c1 = pf1, c2 = pf2, c3 = pf3, cxv = pfx;
    int csid = pfs; bool cval = pfv;
    if (q == 0) {
      int p = base + NPT + nn;
      pfv = p < n;
      int pcl = pfv ? p : (n - 1);
      const float* pp = pc + (size_t)pcl * 5;
      pf1 = pp[1]; pf2 = pp[2]; pf3 = pp[3]; pfx = pp[4];
      pfs = sid[pcl];
    }

    // centroid running sums (sorted ids -> transition flush)
    if (q == 0 && cval) {
      if (csid != cseg) {
        if (cc > 0.f) {
          atomicAdd(&sums[cseg * 4 + 0], cx);
          atomicAdd(&sums[cseg * 4 + 1], cy);
          atomicAdd(&sums[cseg * 4 + 2], cz);
          atomicAdd(&sums[cseg * 4 + 3], cc);
        }
        cseg = csid; cx = 0.f; cy = 0.f; cz = 0.f; cc = 0.f;
      }
      cx += c1; cy += c2; cz += c3; cc += 1.f;
    }

    // per-point segment ids (pull from lanes 0..15)
    int sgl  = __shfl(csid, nn);
    int smin = __builtin_amdgcn_readfirstlane(__shfl(csid, 0));
    int smax = __builtin_amdgcn_readfirstlane(__shfl(csid, NPT - 1));

    if (smin != s_cur) {   // previous segment ended exactly at tile edge
      #pragma unroll
      for (int mt = 0; mt < 16; ++mt) {
        flush_mt(run[mt], mt, s_cur, q, nn, b3, pooled);
        run[mt] = (f32x4){-FLT_MAX, -FLT_MAX, -FLT_MAX, -FLT_MAX};
      }
      s_cur = smin;
    }
    const int  s_before = s_cur;
    const bool fast = (smin == smax);

    // ---- layer 1: B = points (q==0 lanes, k=4 is the bias-ones row) ----
    bf16x8 bO = zero8;
    if (q == 0) {
      bO[0] = (__bf16)cxv;   // x first (concat order!)
      bO[1] = (__bf16)c1;
      bO[2] = (__bf16)c2;
      bO[3] = (__bf16)c3;
      bO[4] = (__bf16)1.0f;  // bias row
    }
    #pragma unroll
    for (int mt = 0; mt < 4; ++mt) {
      f32x4 a = __builtin_amdgcn_mfma_f32_16x16x32_bf16(w1r[mt], bO, zero4, 0, 0, 0);
      bf16x4 pk;
      #pragma unroll
      for (int r = 0; r < 4; ++r) pk[r] = (__bf16)fmaxf(a[r], 0.f);
      *reinterpret_cast<bf16x4*>(&act[w][nn][mt * 16 + q * 4]) = pk;
    }

    bf16x8 f2[2];
    #pragma unroll
    for (int ks = 0; ks < 2; ++ks)
      f2[ks] = *reinterpret_cast<const bf16x8*>(&act[w][nn][ks * 32 + q * 8]);

    // ---- layer 2: act2 overwrites act1 rows (act1 dead after f2 loads) ----
    #pragma unroll
    for (int mt = 0; mt < 8; ++mt) {
      f32x4 a = zero4;
      a = __builtin_amdgcn_mfma_f32_16x16x32_bf16(w2lds[(mt * 2 + 0) * 64 + lane], f2[0], a, 0, 0, 0);
      a = __builtin_amdgcn_mfma_f32_16x16x32_bf16(w2lds[(mt * 2 + 1) * 64 + lane], f2[1], a, 0, 0, 0);
      f32x4 bb = *reinterpret_cast<const f32x4*>(&b2lds[mt * 16 + q * 4]);
      bf16x4 pk;
      #pragma unroll
      for (int r = 0; r < 4; ++r) pk[r] = (__bf16)fmaxf(a[r] + bb[r], 0.f);
      *reinterpret_cast<bf16x4*>(&act[w][nn][mt * 16 + q * 4]) = pk;
    }

    bf16x8 f3[4];
    #pragma unroll
    for (int ks = 0; ks < 4; ++ks)
      f3[ks] = *reinterpret_cast<const bf16x8*>(&act[w][nn][ks * 32 + q * 8]);

    // ---- layer 3 + segment max, m-tile sequential (keeps acc live-range = 1) ----
    #pragma unroll
    for (int mt = 0; mt < 16; ++mt) {
      f32x4 a = zero4;
      #pragma unroll
      for (int ks = 0; ks < 4; ++ks)
        a = __builtin_amdgcn_mfma_f32_16x16x32_bf16(w3lds[(mt * 4 + ks) * 64 + lane], f3[ks], a, 0, 0, 0);
      if (fast) {
        #pragma unroll
        for (int r = 0; r < 4; ++r) run[mt][r] = fmaxf(run[mt][r], a[r]);
      } else {
        // tile crosses >=1 boundary (rare, ~0.4% of tiles)
        for (int s = smin; s <= smax; ++s) {
          f32x4 tmp;
          #pragma unroll
          for (int r = 0; r < 4; ++r) tmp[r] = (sgl == s) ? a[r] : -FLT_MAX;
          if (s < smax) {
            if (s == s_before) {
              #pragma unroll
              for (int r = 0; r < 4; ++r) run[mt][r] = fmaxf(run[mt][r], tmp[r]);
              flush_mt(run[mt], mt, s, q, nn, b3, pooled);
              run[mt] = (f32x4){-FLT_MAX, -FLT_MAX, -FLT_MAX, -FLT_MAX};
            } else {
              flush_mt(tmp, mt, s, q, nn, b3, pooled);
            }
          } else {
            #pragma unroll
            for (int r = 0; r < 4; ++r) run[mt][r] = fmaxf(run[mt][r], tmp[r]);
          }
        }
      }
    }
    if (!fast) s_cur = smax;
  }

  // final flushes
  #pragma unroll
  for (int mt = 0; mt < 16; ++mt)
    flush_mt(run[mt], mt, s_cur, q, nn, b3, pooled);
  if (q == 0 && cc > 0.f) {
    atomicAdd(&sums[cseg * 4 + 0], cx);
    atomicAdd(&sums[cseg * 4 + 1], cy);
    atomicAdd(&sums[cseg * 4 + 2], cz);
    atomicAdd(&sums[cseg * 4 + 3], cc);
  }
}

// ---------------- head: pooled @ Wf + bf -> softplus, + centroid ----------------
__global__ void final_kernel(const float* __restrict__ sums, const unsigned* __restrict__ pooled,
                             const float* __restrict__ Wf, const float* __restrict__ bfv,
                             float* __restrict__ out) {
  __shared__ float red[4][3];
  int g = blockIdx.x;
  int t = threadIdx.x;   // 256 = LAT
  unsigned u = pooled[g * LAT + t];
  float f = u ? unmapf(u) : 0.f;
  float s0 = f * Wf[t * 3 + 0];
  float s1 = f * Wf[t * 3 + 1];
  float s2 = f * Wf[t * 3 + 2];
  #pragma unroll
  for (int off = 1; off < 64; off <<= 1) {
    s0 += __shfl_xor(s0, off);
    s1 += __shfl_xor(s1, off);
    s2 += __shfl_xor(s2, off);
  }
  int wave = t >> 6;
  if ((t & 63) == 0) { red[wave][0] = s0; red[wave][1] = s1; red[wave][2] = s2; }
  __syncthreads();
  if (t < 3) {
    float acc = bfv[t] + red[0][t] + red[1][t] + red[2][t] + red[3][t];
    float sp  = fmaxf(acc, 0.f) + log1pf(expf(-fabsf(acc)));
    float cnt = fmaxf(sums[g * 4 + 3], 1.f);
    float cen = sums[g * 4 + t] / cnt;
    out[g * 3 + t] = cen + sp;
  }
}

extern "C" void kernel_launch(void* const* d_in, const int* in_sizes, int n_in,
                              void* d_out, int out_size, void* d_ws, size_t ws_size,
                              hipStream_t stream) {
  const float* pc  = (const float*)d_in[0];
  const float* W1  = (const float*)d_in[1];
  const float* b1  = (const float*)d_in[2];
  const float* W2  = (const float*)d_in[3];
  const float* b2  = (const float*)d_in[4];
  const float* W3  = (const float*)d_in[5];
  const float* b3  = (const float*)d_in[6];
  const float* Wf  = (const float*)d_in[7];
  const float* bfv = (const float*)d_in[8];
  const int*   sid = (const int*)d_in[9];
  int n = in_sizes[0] / 5;

  float*    sums   = (float*)d_ws;                         // G*4 fp32
  unsigned* pooled = (unsigned*)((char*)d_ws + 4096);      // G*LAT mapped-uint maxes
  hipMemsetAsync(d_ws, 0, 4096 + (size_t)G * LAT * 4, stream);

  int tiles       = (n + NPT - 1) / NPT;
  int nblocks     = 256;                     // 1 block/CU (114.5 KB LDS), 8 indep waves
  int waves_total = nblocks * NW;
  int tpw         = (tiles + waves_total - 1) / waves_total;
  mlp_kernel<<<nblocks, 512, 0, stream>>>(pc, W1, b1, W2, b2, W3, b3, sid, pooled, sums, n, tpw);

  final_kernel<<<G, 256, 0, stream>>>(sums, pooled, Wf, bfv, (float*)d_out);
}